// Round 9
// baseline (355.114 us; speedup 1.0000x reference)
//
#include <hip/hip_runtime.h>
#include <hip/hip_bf16.h>
#include <hip/hip_cooperative_groups.h>
#include <stdint.h>

// QSCrossAttention: B=8, Nq=1024, Nkv=4096, D=512, fp32 I/O, bf16 MFMA compute.
// R17: R16's fused cooperative mega-kernel, launch made robust. R16's absmax
//      0.048 == max|ref| -> output was never written: the coop launch (768
//      blocks, needed exactly 3/CU) silently failed. Now: grid 512 at
//      lb(256,2) (VGPR budget 256 >> ~150 used, capacity >= 2/CU guaranteed),
//      return code CHECKED, permanent fallback to a 7-dispatch sequence built
//      from the same proven tile bodies if coop ever errors.

namespace cg = cooperative_groups;

typedef __bf16 bf16;
typedef bf16 bf16x8 __attribute__((ext_vector_type(8)));
typedef bf16 bf16x4 __attribute__((ext_vector_type(4)));
typedef float f32x4 __attribute__((ext_vector_type(4)));

#define NB 8
#define NQ 1024
#define NKV 4096
#define DD 512
#define RT_LD 136
#define NBLK 512
#define SCALE 0.04419417382415922f

__device__ __forceinline__ void lds16(const bf16* g, bf16* l) {
  __builtin_amdgcn_global_load_lds(
      (const __attribute__((address_space(1))) unsigned int*)g,
      (__attribute__((address_space(3))) unsigned int*)l, 16, 0, 0);
}

// ---- scan body: 3-mode sniff + denom zero + per-batch prefix scan ---------
__device__ void scan_dev(int* ips, const void* mask, int* idx, int* cnt,
                         int* kpad, float* denom, int b, int tid) {
  for (int i = tid; i < NQ; i += 256) denom[b * NQ + i] = 0.f;
  if (tid == 0) { ips[256] = 0; ips[257] = 0; }
  __syncthreads();
  {
    const unsigned* mw = (const unsigned*)mask;
    int b0 = 0, b1 = 0;
    for (int i = tid; i < 8192; i += 256) {
      unsigned v = mw[i];
      if (v > 1u) b0 = 1;
      if (v != 0u && v != 0x3F800000u) b1 = 1;
    }
    if (b0) atomicOr(&ips[256], 1);
    if (b1) atomicOr(&ips[257], 1);
  }
  __syncthreads();
  const int mode = (ips[256] == 0) ? 0 : ((ips[257] == 0) ? 1 : 2);
  __syncthreads();

  unsigned bits = 0;
  int c = 0;
  const int base = tid * 16;
  for (int i = 0; i < 16; ++i) {
    const int col = base + i;
    bool k;
    if (mode == 0)      k = ((const int*)mask)[b * NKV + col] != 0;
    else if (mode == 1) k = ((const float*)mask)[b * NKV + col] != 0.f;
    else                k = ((const unsigned char*)mask)[b * NKV + col] != 0;
    bits |= (unsigned)k << i;
    c += k;
  }
  ips[tid] = c;
  __syncthreads();
  for (int s = 1; s < 256; s <<= 1) {
    int v = (tid >= s) ? ips[tid - s] : 0;
    __syncthreads();
    ips[tid] += v;
    __syncthreads();
  }
  int off = ips[tid] - c;
  for (int i = 0; i < 16; ++i)
    if ((bits >> i) & 1) idx[b * NKV + off++] = base + i;
  if (tid == 255) {
    cnt[b] = ips[255];
    kpad[b] = (ips[255] + 127) & ~127;
  }
}

// ---- prep body: gather (vb<2048) | cvt proto (<6144) | cvt weights --------
__device__ void prep_dev(int blk, int tid,
                         const float* qx, const int* idx, const int* cnt,
                         const int* kpad, bf16* qc,
                         const float* proto, bf16* proto_b,
                         const float* Wq, const float* Wk, const float* Wv,
                         const float* Wp, bf16* Wq_b, bf16* Wkv_b, bf16* Wp_b) {
  if (blk < 2048) {
    const int b = blk >> 8, bx = blk & 255;
    const int wave = tid >> 6, lane = tid & 63;
    const int r0 = bx * 16 + wave * 4;
    const int n = cnt[b];
    const int kp = kpad[b];
#pragma unroll
    for (int j = 0; j < 4; ++j) {
      const int row = r0 + j;
      if (row >= kp) break;
      bf16x4* d = (bf16x4*)(qc + ((long)b * NKV + row) * DD) + lane;
      if (row < n) {
        const int src = idx[b * NKV + row];
        const float4* s = (const float4*)(qx + ((long)b * NKV + src) * DD) + lane;
        float4 v0 = s[0], v1 = s[64];
        bf16x4 o0, o1;
        o0.x = (bf16)v0.x; o0.y = (bf16)v0.y; o0.z = (bf16)v0.z; o0.w = (bf16)v0.w;
        o1.x = (bf16)v1.x; o1.y = (bf16)v1.y; o1.z = (bf16)v1.z; o1.w = (bf16)v1.w;
        d[0] = o0;
        d[64] = o1;
      } else {
        bf16x4 z;
        z.x = (bf16)0.f; z.y = (bf16)0.f; z.z = (bf16)0.f; z.w = (bf16)0.f;
        d[0] = z;
        d[64] = z;
      }
    }
  } else if (blk < 6144) {
    const int i = (blk - 2048) * 256 + tid;
    float4 v = ((const float4*)proto)[i];
    bf16x4 o;
    o.x = (bf16)v.x; o.y = (bf16)v.y; o.z = (bf16)v.z; o.w = (bf16)v.w;
    ((bf16x4*)proto_b)[i] = o;
  } else {
    const int j = (blk - 6144) * 256 + tid;
    const int w = j >> 16, r = j & 65535;
    const float* src = (w == 0) ? Wq : (w == 1) ? Wk : (w == 2) ? Wv : Wp;
    bf16x4* dst = (w == 0) ? (bf16x4*)Wq_b
                : (w == 3) ? (bf16x4*)Wp_b
                           : (bf16x4*)Wkv_b + (w == 2 ? 65536 : 0);
    float4 v = ((const float4*)src)[r];
    bf16x4 o;
    o.x = (bf16)v.x; o.y = (bf16)v.y; o.z = (bf16)v.z; o.w = (bf16)v.w;
    dst[r] = o;
  }
}

// ---- 128x128-tile GEMM body (BK=32, 2-barrier, 17.4KB LDS; R14-proven) ----
template <int EPI>
__device__ void gemm_tile(bf16* Smem, const bf16* A, const bf16* Bw,
                          void* Cp, void* Cp2, int N, int Kstride,
                          long sA, long sB, long sC,
                          const int* cnt, float* denom, int M,
                          int bx, int by, int b, int tid) {
  bf16* As = Smem;
  bf16* Bs = Smem + 4096;
  bf16* Rt = Smem;  // 64-row epilogue overlay [64][RT_LD]
  const int wave = tid >> 6, lane = tid & 63;
  const int l15 = lane & 15, l4 = lane >> 4;
  const int wm = (wave >> 1) * 64, wn = (wave & 1) * 64;

  const bf16* Ab = A + (long)b * sA + (long)(by * 128) * Kstride;
  const bf16* Bb = Bw + (long)b * sB + (long)(bx * 128) * Kstride;

  const int c0 = wave * 2, c1 = wave * 2 + 1;
  const int srow = lane >> 2;
  const int scol = (lane & 3) * 8;
  const bf16* ag0 = Ab + (long)(c0 * 16 + srow) * Kstride + scol;
  const bf16* ag1 = Ab + (long)(c1 * 16 + srow) * Kstride + scol;
  const bf16* bg0 = Bb + (long)(c0 * 16 + srow) * Kstride + scol;
  const bf16* bg1 = Bb + (long)(c1 * 16 + srow) * Kstride + scol;
  bf16* al0 = As + c0 * 512;
  bf16* al1 = As + c1 * 512;
  bf16* bl0 = Bs + c0 * 512;
  bf16* bl1 = Bs + c1 * 512;

  f32x4 acc[4][4] = {};

  for (int kt = 0; kt < DD; kt += 32) {
    __syncthreads();
    lds16(ag0, al0);
    lds16(ag1, al1);
    lds16(bg0, bl0);
    lds16(bg1, bl1);
    ag0 += 32; ag1 += 32; bg0 += 32; bg1 += 32;
    __syncthreads();
    bf16x8 af[4], bfr[4];
#pragma unroll
    for (int t = 0; t < 4; ++t)
      af[t] = *(const bf16x8*)(As + (wm + t * 16 + l15) * 32 + l4 * 8);
#pragma unroll
    for (int t = 0; t < 4; ++t)
      bfr[t] = *(const bf16x8*)(Bs + (wn + t * 16 + l15) * 32 + l4 * 8);
#pragma unroll
    for (int mt = 0; mt < 4; ++mt)
#pragma unroll
      for (int nt = 0; nt < 4; ++nt)
        acc[mt][nt] = __builtin_amdgcn_mfma_f32_16x16x32_bf16(af[mt], bfr[nt],
                                                              acc[mt][nt], 0, 0, 0);
  }

  const int rowBase = by * 128 + wm;
  const int colBase = bx * 128 + wn;
  const int tR = by * 128;
  const int tC = bx * 128;
  const int r0 = tid >> 2, cq = (tid & 3) * 32;

  __syncthreads();  // K-loop LDS dead before Rt overlay

  if constexpr (EPI == 2) {
    bf16* C = (bf16*)Cp + (long)b * sC;
    const int nkeep = cnt[b];
    float rs[4][4];
#pragma unroll
    for (int mt = 0; mt < 4; ++mt)
#pragma unroll
      for (int r = 0; r < 4; ++r) rs[mt][r] = 0.f;
#pragma unroll
    for (int nt = 0; nt < 4; ++nt) {
      const bool keep = (colBase + nt * 16 + l15) < nkeep;
#pragma unroll
      for (int mt = 0; mt < 4; ++mt)
#pragma unroll
        for (int r = 0; r < 4; ++r)
          rs[mt][r] += keep ? __expf(acc[mt][nt][r] * SCALE) : 0.f;
    }
#pragma unroll
    for (int mt = 0; mt < 4; ++mt)
#pragma unroll
      for (int r = 0; r < 4; ++r) {
        float v = rs[mt][r];
        v += __shfl_xor(v, 1, 64);
        v += __shfl_xor(v, 2, 64);
        v += __shfl_xor(v, 4, 64);
        v += __shfl_xor(v, 8, 64);
        if (l15 == 0)
          atomicAdd(&denom[b * M + rowBase + mt * 16 + l4 * 4 + r], v);
      }
#pragma unroll
    for (int ph = 0; ph < 2; ++ph) {
      if (wm == ph * 64) {
#pragma unroll
        for (int nt = 0; nt < 4; ++nt) {
          const bool keep = (colBase + nt * 16 + l15) < nkeep;
#pragma unroll
          for (int mt = 0; mt < 4; ++mt)
#pragma unroll
            for (int r = 0; r < 4; ++r) {
              float p = keep ? __expf(acc[mt][nt][r] * SCALE) : 0.f;
              Rt[(mt * 16 + l4 * 4 + r) * RT_LD + wn + nt * 16 + l15] = (bf16)p;
            }
        }
      }
      __syncthreads();
#pragma unroll
      for (int j = 0; j < 4; ++j) {
        bf16x8 v = *(const bf16x8*)(Rt + r0 * RT_LD + cq + j * 8);
        *(bf16x8*)(C + (long)(tR + ph * 64 + r0) * N + tC + cq + j * 8) = v;
      }
      __syncthreads();
    }
  } else if constexpr (EPI == 0) {
    bf16* C = (bf16*)Cp;
#pragma unroll
    for (int ph = 0; ph < 2; ++ph) {
      if (wm == ph * 64) {
#pragma unroll
        for (int mt = 0; mt < 4; ++mt)
#pragma unroll
          for (int nt = 0; nt < 4; ++nt)
#pragma unroll
            for (int r = 0; r < 4; ++r)
              Rt[(mt * 16 + l4 * 4 + r) * RT_LD + wn + nt * 16 + l15] =
                  (bf16)acc[mt][nt][r];
      }
      __syncthreads();
#pragma unroll
      for (int j = 0; j < 4; ++j) {
        bf16x8 v = *(const bf16x8*)(Rt + r0 * RT_LD + cq + j * 8);
        *(bf16x8*)(C + (long)(tR + ph * 64 + r0) * N + tC + cq + j * 8) = v;
      }
      __syncthreads();
    }
  } else if constexpr (EPI == 4) {
    float* C = (float*)Cp;
#pragma unroll
    for (int mt = 0; mt < 4; ++mt)
#pragma unroll
      for (int nt = 0; nt < 4; ++nt)
#pragma unroll
        for (int r = 0; r < 4; ++r)
          C[(long)(tR + wm + mt * 16 + l4 * 4 + r) * N + tC + wn + nt * 16 + l15] =
              acc[mt][nt][r];
    __syncthreads();
  } else {  // EPI == 5
    if (tC < 512) {
      bf16* C = (bf16*)Cp;  // k: [B*NKV][512]
#pragma unroll
      for (int ph = 0; ph < 2; ++ph) {
        if (wm == ph * 64) {
#pragma unroll
          for (int mt = 0; mt < 4; ++mt)
#pragma unroll
            for (int nt = 0; nt < 4; ++nt)
#pragma unroll
              for (int r = 0; r < 4; ++r)
                Rt[(mt * 16 + l4 * 4 + r) * RT_LD + wn + nt * 16 + l15] =
                    (bf16)acc[mt][nt][r];
        }
        __syncthreads();
#pragma unroll
        for (int j = 0; j < 4; ++j) {
          bf16x8 v = *(const bf16x8*)(Rt + r0 * RT_LD + cq + j * 8);
          *(bf16x8*)(C + (long)(tR + ph * 64 + r0) * 512 + tC + cq + j * 8) = v;
        }
        __syncthreads();
      }
    } else {
      bf16* C = (bf16*)Cp2;  // vT: [B][512][NKV]
      const int bb = tR >> 12, kvloc = tR & 4095;
#pragma unroll
      for (int ph = 0; ph < 2; ++ph) {
        if (wn == ph * 64) {
#pragma unroll
          for (int mt = 0; mt < 4; ++mt) {
            const int rr = wm + mt * 16 + l4 * 4;
#pragma unroll
            for (int nt = 0; nt < 4; ++nt) {
              const int cloc = nt * 16 + l15;
              bf16x4 o;
              o.x = (bf16)acc[mt][nt][0]; o.y = (bf16)acc[mt][nt][1];
              o.z = (bf16)acc[mt][nt][2]; o.w = (bf16)acc[mt][nt][3];
              *(bf16x4*)(Rt + cloc * RT_LD + rr) = o;
            }
          }
        }
        __syncthreads();
#pragma unroll
        for (int j = 0; j < 4; ++j) {
          bf16x8 v = *(const bf16x8*)(Rt + r0 * RT_LD + cq + j * 8);
          *(bf16x8*)(C + (long)bb * DD * NKV +
                     (long)(tC - 512 + ph * 64 + r0) * NKV + kvloc + cq + j * 8) = v;
        }
        __syncthreads();
      }
    }
  }
}

// ---- PV body: x = (P @ vT^T)/denom, 64q x 128d, K = kpad[b] ---------------
__device__ void pv_tile(bf16* Smem, const bf16* P, const bf16* vT,
                        const float* denom, const int* kpad,
                        bf16* x, int qb, int db, int b, int tid) {
  bf16* As = Smem;
  bf16* Bs = Smem + 2048;
  bf16* Rt = Smem;
  const int wave = tid >> 6, lane = tid & 63;
  const int l15 = lane & 15, l4 = lane >> 4;
  const int wm = (wave >> 1) * 32, wn = (wave & 1) * 64;
  const int qB = qb * 64;
  const int dB = db * 128;
  const int Kb = kpad[b];

  const bf16* Ab = P + (long)b * NQ * NKV + (long)qB * NKV;
  const bf16* Bb = vT + (long)b * DD * NKV + (long)dB * NKV;

  const int srow = lane >> 2, scol = (lane & 3) * 8;
  const int c0 = wave * 2, c1 = wave * 2 + 1;
  const bf16* ag  = Ab + (long)(wave * 16 + srow) * NKV + scol;
  const bf16* bg0 = Bb + (long)(c0 * 16 + srow) * NKV + scol;
  const bf16* bg1 = Bb + (long)(c1 * 16 + srow) * NKV + scol;
  bf16* la  = As + wave * 512;
  bf16* lb0 = Bs + c0 * 512;
  bf16* lb1 = Bs + c1 * 512;

  f32x4 acc[2][4] = {};

  for (int kt = 0; kt < Kb; kt += 32) {
    __syncthreads();
    lds16(ag, la);
    lds16(bg0, lb0);
    lds16(bg1, lb1);
    ag += 32; bg0 += 32; bg1 += 32;
    __syncthreads();
    bf16x8 af[2], bfr[4];
#pragma unroll
    for (int t = 0; t < 2; ++t)
      af[t] = *(const bf16x8*)(As + (wm + t * 16 + l15) * 32 + l4 * 8);
#pragma unroll
    for (int t = 0; t < 4; ++t)
      bfr[t] = *(const bf16x8*)(Bs + (wn + t * 16 + l15) * 32 + l4 * 8);
#pragma unroll
    for (int mt = 0; mt < 2; ++mt)
#pragma unroll
      for (int nt = 0; nt < 4; ++nt)
        acc[mt][nt] = __builtin_amdgcn_mfma_f32_16x16x32_bf16(af[mt], bfr[nt],
                                                              acc[mt][nt], 0, 0, 0);
  }

  __syncthreads();
#pragma unroll
  for (int mt = 0; mt < 2; ++mt)
#pragma unroll
    for (int r = 0; r < 4; ++r) {
      const int row = wm + mt * 16 + l4 * 4 + r;
      const float inv = 1.0f / denom[b * NQ + qB + row];
#pragma unroll
      for (int nt = 0; nt < 4; ++nt)
        Rt[row * RT_LD + wn + nt * 16 + l15] = (bf16)(acc[mt][nt][r] * inv);
    }
  __syncthreads();
  const int r0 = tid >> 2, cq = (tid & 3) * 32;
#pragma unroll
  for (int j = 0; j < 4; ++j) {
    bf16x8 v = *(const bf16x8*)(Rt + r0 * RT_LD + cq + j * 8);
    *(bf16x8*)(x + (long)(b * NQ + qB + r0) * DD + dB + cq + j * 8) = v;
  }
  __syncthreads();
}

// --------------------------- fused mega-kernel -----------------------------
__global__ void __launch_bounds__(256, 2)
fused(const float* __restrict__ proto, const float* __restrict__ qx,
      const void* __restrict__ mask,
      const float* __restrict__ Wq, const float* __restrict__ Wk,
      const float* __restrict__ Wv, const float* __restrict__ Wp,
      float* __restrict__ out,
      int* idx, int* cnt, int* kpad, float* denom,
      bf16* Wq_b, bf16* Wkv_b, bf16* Wp_b,
      bf16* q_b, bf16* k_b, bf16* vT_b, bf16* x_b,
      bf16* proto_b, bf16* qc_b, bf16* P) {
  cg::grid_group grid = cg::this_grid();
  __shared__ alignas(16) bf16 Smem[8704];  // 17408 B
  const int bid = blockIdx.x, tid = threadIdx.x;

  if (bid < 8) scan_dev((int*)Smem, mask, idx, cnt, kpad, denom, bid, tid);
  __threadfence();
  grid.sync();

  for (int vb = bid; vb < 7168; vb += NBLK)
    prep_dev(vb, tid, qx, idx, cnt, kpad, qc_b, proto, proto_b,
             Wq, Wk, Wv, Wp, Wq_b, Wkv_b, Wp_b);
  __threadfence();
  grid.sync();

  int kp[8], kvp[9], sp[9];
  kvp[0] = 0; sp[0] = 0;
#pragma unroll
  for (int i = 0; i < 8; ++i) {
    kp[i] = kpad[i];
    const int t128 = kp[i] >> 7;
    kvp[i + 1] = kvp[i] + t128 * 8;
    sp[i + 1] = sp[i] + t128 * 8;
  }

  // q-proj (256 tiles) + kv-proj (live tiles)
  {
    const int tot = 256 + kvp[8];
    for (int vt = bid; vt < tot; vt += NBLK) {
      if (vt < 256) {
        gemm_tile<0>(Smem, proto_b, Wq_b, q_b, nullptr, DD, DD, 0L, 0L, 0L,
                     cnt, nullptr, 0, vt & 3, vt >> 2, 0, tid);
      } else {
        int i = vt - 256;
        int bb = 0;
        while (i >= kvp[bb + 1]) ++bb;
        const int rem = i - kvp[bb];
        const int rows = kp[bb] >> 7;
        const int cx = rem / rows;
        const int lr = rem - cx * rows;
        gemm_tile<5>(Smem, qc_b, Wkv_b, k_b, vT_b, 1024, DD, 0L, 0L, 0L,
                     cnt, nullptr, 0, cx, bb * 32 + lr, 0, tid);
      }
    }
  }
  __threadfence();
  grid.sync();

  // S = exp(scale * q @ k^T), live tiles
  for (int vt = bid; vt < sp[8]; vt += NBLK) {
    int bb = 0;
    while (vt >= sp[bb + 1]) ++bb;
    const int rem = vt - sp[bb];
    const int cols = kp[bb] >> 7;
    const int bx = rem % cols;
    const int by = rem / cols;
    gemm_tile<2>(Smem, q_b, k_b, P, nullptr, NKV, DD,
                 (long)NQ * DD, (long)NKV * DD, (long)NQ * NKV,
                 cnt, denom, NQ, bx, by, bb, tid);
  }
  __threadfence();
  grid.sync();

  // PV (512 tiles)
  for (int vt = bid; vt < 512; vt += NBLK)
    pv_tile(Smem, P, vT_b, denom, kpad, x_b, vt & 15, (vt >> 4) & 3, vt >> 6, tid);
  __threadfence();
  grid.sync();

  // out-proj (256 tiles)
  for (int vt = bid; vt < 256; vt += NBLK)
    gemm_tile<4>(Smem, x_b, Wp_b, out, nullptr, DD, DD, 0L, 0L, 0L,
                 cnt, nullptr, 0, vt & 3, vt >> 2, 0, tid);
}

// --------------------- fallback wrappers (7 dispatches) --------------------
__global__ void __launch_bounds__(256)
scan_k(const void* mask, int* idx, int* cnt, int* kpad, float* denom) {
  __shared__ int ips[258];
  scan_dev(ips, mask, idx, cnt, kpad, denom, blockIdx.x, threadIdx.x);
}

__global__ void __launch_bounds__(256)
prep_k(const float* qx, const int* idx, const int* cnt, const int* kpad,
       bf16* qc, const float* proto, bf16* proto_b,
       const float* Wq, const float* Wk, const float* Wv, const float* Wp,
       bf16* Wq_b, bf16* Wkv_b, bf16* Wp_b) {
  prep_dev(blockIdx.x, threadIdx.x, qx, idx, cnt, kpad, qc, proto, proto_b,
           Wq, Wk, Wv, Wp, Wq_b, Wkv_b, Wp_b);
}

template <int EPI>
__global__ void __launch_bounds__(256, 3)
gemm_k(const bf16* A, const bf16* Bw, void* Cp, void* Cp2,
       int N, int Kstride, long sA, long sB, long sC,
       const int* cnt, const int* kpad, float* denom, int M) {
  __shared__ alignas(16) bf16 Smem[8704];
  int bx, by, b;
  if constexpr (EPI == 5) {
    bx = blockIdx.y; by = blockIdx.x; b = 0;
    const int bb = by >> 5, loc = (by & 31) * 128;
    if (loc >= kpad[bb]) return;
  } else {
    bx = blockIdx.x; by = blockIdx.y; b = blockIdx.z;
    if constexpr (EPI == 2) {
      if (bx * 128 >= kpad[b]) return;
    }
  }
  gemm_tile<EPI>(Smem, A, Bw, Cp, Cp2, N, Kstride, sA, sB, sC,
                 cnt, denom, M, bx, by, b, threadIdx.x);
}

__global__ void __launch_bounds__(256, 3)
pv_k(const bf16* P, const bf16* vT, const float* denom, const int* kpad,
     bf16* x) {
  __shared__ alignas(16) bf16 Smem[8704];
  pv_tile(Smem, P, vT, denom, kpad, x, blockIdx.x, blockIdx.y, blockIdx.z,
          threadIdx.x);
}

static int g_coop_broken = 0;

extern "C" void kernel_launch(void* const* d_in, const int* in_sizes, int n_in,
                              void* d_out, int out_size, void* d_ws, size_t ws_size,
                              hipStream_t stream) {
  const float* proto = (const float*)d_in[0];
  const float* qx    = (const float*)d_in[1];
  const void*  mask  = d_in[2];
  const float* Wq    = (const float*)d_in[3];
  const float* Wk    = (const float*)d_in[4];
  const float* Wv    = (const float*)d_in[5];
  const float* Wproj = (const float*)d_in[6];
  float* out = (float*)d_out;

  char* w = (char*)d_ws;
  int*   cnt   = (int*)(w + 64);
  int*   kpadA = (int*)(w + 128);
  float* denom = (float*)(w + 4096);
  size_t off = 65536;
  bf16* Wq_b  = (bf16*)(w + off); off += (size_t)DD * DD * 2;
  bf16* Wkv_b = (bf16*)(w + off); off += (size_t)DD * DD * 4;
  bf16* Wp_b  = (bf16*)(w + off); off += (size_t)DD * DD * 2;
  int*  idx   = (int*)(w + off);  off += (size_t)NB * NKV * 4;
  bf16* q_b   = (bf16*)(w + off); off += (size_t)NB * NQ * DD * 2;   // 8MB
  bf16* k_b   = (bf16*)(w + off); off += (size_t)NB * NKV * DD * 2;  // 32MB
  bf16* vT_b  = (bf16*)(w + off); off += (size_t)NB * NKV * DD * 2;  // 32MB
  bf16* x_b   = (bf16*)(w + off); off += (size_t)NB * NQ * DD * 2;   // 8MB
  size_t off_pp = off;
  bf16* proto_b = (bf16*)(w + off); off += (size_t)NB * NQ * DD * 2;
  bf16* qc_b    = (bf16*)(w + off);
  bf16* P       = (bf16*)(w + off_pp);   // 64MB, overlays proto/qc (dead by S)

  if (!g_coop_broken) {
    void* args[] = {
        (void*)&proto, (void*)&qx, (void*)&mask,
        (void*)&Wq, (void*)&Wk, (void*)&Wv, (void*)&Wproj,
        (void*)&out,
        (void*)&idx, (void*)&cnt, (void*)&kpadA, (void*)&denom,
        (void*)&Wq_b, (void*)&Wkv_b, (void*)&Wp_b,
        (void*)&q_b, (void*)&k_b, (void*)&vT_b, (void*)&x_b,
        (void*)&proto_b, (void*)&qc_b, (void*)&P};
    hipError_t e = hipLaunchCooperativeKernel((const void*)fused, dim3(NBLK),
                                              dim3(256), args, 0, stream);
    if (e == hipSuccess) return;
    g_coop_broken = 1;
    (void)hipGetLastError();  // clear sticky error
  }

  // ---- fallback: proven 7-dispatch sequence --------------------------------
  scan_k<<<8, 256, 0, stream>>>(mask, idx, cnt, kpadA, denom);
  prep_k<<<7168, 256, 0, stream>>>(qx, idx, cnt, kpadA, qc_b,
                                   proto, proto_b, Wq, Wk, Wv, Wproj,
                                   Wq_b, Wkv_b, Wp_b);
  gemm_k<0><<<dim3(4, 64, 1), 256, 0, stream>>>(
      proto_b, Wq_b, q_b, nullptr, DD, DD, 0L, 0L, 0L, cnt, kpadA, nullptr, 0);
  gemm_k<5><<<dim3(256, 8, 1), 256, 0, stream>>>(
      qc_b, Wkv_b, k_b, vT_b, 1024, DD, 0L, 0L, 0L, cnt, kpadA, nullptr, 0);
  gemm_k<2><<<dim3(NKV / 128, NQ / 128, NB), 256, 0, stream>>>(
      q_b, k_b, P, nullptr, NKV, DD,
      (long)NQ * DD, (long)NKV * DD, (long)NQ * NKV, cnt, kpadA, denom, NQ);
  pv_k<<<dim3(16, 4, 8), 256, 0, stream>>>(P, vT_b, denom, kpadA, x_b);
  gemm_k<4><<<dim3(4, 64, 1), 256, 0, stream>>>(
      x_b, Wp_b, out, nullptr, DD, DD, 0L, 0L, 0L, cnt, kpadA, nullptr, 0);
}